// Round 13
// baseline (203.783 us; speedup 1.0000x reference)
//
#include <hip/hip_runtime.h>
#include <math.h>

#define NN 131072
#define MM 256
#define HH 1024

typedef float nat_f4 __attribute__((ext_vector_type(4)));

// DIAGNOSTIC BUILD 2: score body x8, update body x2 (idempotent repeats).
// Resolves score_cold-vs-gaps ambiguity + update rep1 cache state.

// ---------------- ws layout (float offsets) ----------------
#define WS_P      0        // raw params[32]
#define WS_GATES  64       // 4096
#define WS_KEY    4160     // 2*256
#define WS_ER     4672     // 256
#define WS_AD     4928     // 256
#define WS_E      8192     // 2*N  (exp(score), unnormalized)
#define WS_WP     270336   // 2*N
#define WS_PSUM   532480   // 2*8192
#define WS_PSUM2  548864   // 2*512
#define WS_RPART  549888   // 1024*256
#define WS_READ   812032   // 256

#define P_RAWB   0   // raw beta [2]
#define P_RAWG   2   // raw gate [2]
#define P_RAWGA  4   // raw gamma [2]
#define P_RAWS   6   // raw shift [2][3]

__device__ __forceinline__ float wave_sum(float v) {
    v += __shfl_xor(v, 32); v += __shfl_xor(v, 16); v += __shfl_xor(v, 8);
    v += __shfl_xor(v, 4);  v += __shfl_xor(v, 2);  v += __shfl_xor(v, 1);
    return v;
}
__device__ __forceinline__ float sigm(float x) { return 1.0f / (1.0f + expf(-x)); }
__device__ __forceinline__ float softplus_(float x) { return x > 20.0f ? x : log1pf(expf(x)); }
__device__ __forceinline__ float dot4(float4 a, float4 b) {
    return a.x * b.x + a.y * b.y + a.z * b.z + a.w * b.w;
}

// K1: gates GEMV
__global__ __launch_bounds__(256) void gates_kernel(
    const float* __restrict__ x, const float* __restrict__ pr, const float* __restrict__ hs,
    const float* __restrict__ Wih, const float* __restrict__ bih,
    const float* __restrict__ Whh, const float* __restrict__ bhh,
    float* __restrict__ gates)
{
    int wid = blockIdx.x * 4 + (threadIdx.x >> 6);   // 0..4095
    int lane = threadIdx.x & 63;
    const float4* wi4 = (const float4*)(Wih + (size_t)wid * 768);
    const float4* wh4 = (const float4*)(Whh + (size_t)wid * 1024);
    const float4* x4  = (const float4*)x;
    const float4* pr4 = (const float4*)pr;
    const float4* hs4 = (const float4*)hs;
    float s = 0.f;
    #pragma unroll
    for (int q = 0; q < 3; q++) {
        int j4 = lane + 64 * q;
        float4 wv = wi4[j4];
        float4 xv = (q < 2) ? x4[j4] : pr4[j4 - 128];
        s += dot4(wv, xv);
    }
    #pragma unroll
    for (int q = 0; q < 4; q++) {
        int j4 = lane + 64 * q;
        s += dot4(wh4[j4], hs4[j4]);
    }
    s = wave_sum(s);
    if (lane == 0) gates[wid] = s + bih[wid] + bhh[wid];
}

// K2: head linears (c recomputed per block in LDS)
__global__ __launch_bounds__(256) void head_prep_kernel(
    const float* __restrict__ gates, const float* __restrict__ cs,
    const float* __restrict__ Wk, const float* __restrict__ bk,
    const float* __restrict__ We, const float* __restrict__ be,
    const float* __restrict__ Wa, const float* __restrict__ ba,
    const float* __restrict__ Ws, const float* __restrict__ bs,
    const float* __restrict__ Wbeta, const float* __restrict__ bbeta,
    const float* __restrict__ Wg, const float* __restrict__ bg,
    const float* __restrict__ Wgamma, const float* __restrict__ bgamma,
    float* __restrict__ key, float* __restrict__ er, float* __restrict__ ad,
    float* __restrict__ params)
{
    __shared__ float c_l[1024];
    int t = threadIdx.x;
    #pragma unroll
    for (int k = 0; k < 4; k++) {
        int j = t + 256 * k;
        float ig = gates[j], fg = gates[1024 + j], gg = gates[2048 + j];
        c_l[j] = sigm(fg) * cs[j] + sigm(ig) * tanhf(gg);
    }
    __syncthreads();

    int wid = blockIdx.x * 4 + (t >> 6);   // 0..1035
    int lane = t & 63;
    const float* wrow; float bias; float* dst; int act;
    if (wid < 512)      { int h = wid >> 8, m = wid & 255; wrow = Wk + (size_t)(h * 256 + m) * 1024; bias = bk[h * 256 + m]; dst = key + wid; act = 0; }
    else if (wid < 768) { int m = wid - 512; wrow = We + (size_t)(256 + m) * 1024; bias = be[256 + m]; dst = er + m; act = 1; }
    else if (wid < 1024){ int m = wid - 768; wrow = Wa + (size_t)(256 + m) * 1024; bias = ba[256 + m]; dst = ad + m; act = 0; }
    else if (wid < 1030){ int k = wid - 1024; wrow = Ws + (size_t)k * 1024; bias = bs[k]; dst = params + P_RAWS + k; act = 2; }
    else                { int k = wid - 1030; int h = k & 1, which = k >> 1;
                          const float* Wp = which == 0 ? Wbeta : (which == 1 ? Wg : Wgamma);
                          const float* bp = which == 0 ? bbeta : (which == 1 ? bg : bgamma);
                          wrow = Wp + h * 1024; bias = bp[h]; dst = params + 2 * which + h; act = 2; }
    const float4* w4 = (const float4*)wrow;
    const float4* c4 = (const float4*)c_l;
    float s = 0.f;
    #pragma unroll
    for (int q = 0; q < 4; q++) {
        int j4 = lane + 64 * q;
        s += dot4(w4[j4], c4[j4]);
    }
    s = wave_sum(s);
    if (lane == 0) {
        s += bias;
        if (act == 0) s = tanhf(s);
        else if (act == 1) s = sigm(s);
        *dst = s;
    }
}

// K3: score+exp — DIAGNOSTIC x8 repeat (idempotent)
__global__ __launch_bounds__(256) void score_exp_kernel(
    const float* __restrict__ mem, const float* __restrict__ key,
    const float* __restrict__ params, float* __restrict__ e, float* __restrict__ psum)
{
    __shared__ float ss_l[2];
    __shared__ float red[8];
    int t = threadIdx.x;
    int w = t >> 6, lane = t & 63;
    {
        float v0 = key[t], v1 = key[256 + t];
        float s0 = v0 * v0, s1 = v1 * v1;
        s0 = wave_sum(s0); s1 = wave_sum(s1);
        if (lane == 0) { red[w] = s0; red[4 + w] = s1; }
        __syncthreads();
        if (t == 0) {
            float k0 = red[0] + red[1] + red[2] + red[3];
            float k1 = red[4] + red[5] + red[6] + red[7];
            ss_l[0] = softplus_(params[P_RAWB])     / fmaxf(sqrtf(k0), 1e-8f);
            ss_l[1] = softplus_(params[P_RAWB + 1]) / fmaxf(sqrtf(k1), 1e-8f);
        }
        __syncthreads();
    }
    int sub = lane & 15, g = lane >> 4;
    int wid = blockIdx.x * 4 + w;          // 0..32767
    int row = wid * 4 + g;                 // 0..131071
    const float4* m4 = (const float4*)mem;
    const float4* k4 = (const float4*)key;
    float4 k0[4], k1[4];
    #pragma unroll
    for (int q = 0; q < 4; q++) {
        k0[q] = k4[sub + 16 * q];
        k1[q] = k4[64 + sub + 16 * q];
    }
    for (int rep = 0; rep < 8; rep++) {    // DIAGNOSTIC repeat
        float4 mv[4];
        #pragma unroll
        for (int q = 0; q < 4; q++) mv[q] = m4[(size_t)row * 64 + sub + 16 * q];
        float d0 = 0.f, d1 = 0.f, sq = 0.f;
        #pragma unroll
        for (int q = 0; q < 4; q++) {
            d0 += dot4(k0[q], mv[q]);
            d1 += dot4(k1[q], mv[q]);
            sq += dot4(mv[q], mv[q]);
        }
        #pragma unroll
        for (int off = 8; off; off >>= 1) {
            d0 += __shfl_xor(d0, off); d1 += __shfl_xor(d1, off); sq += __shfl_xor(sq, off);
        }
        float a0 = 0.f, a1 = 0.f;
        if (sub == 0) {
            float mn = fmaxf(sqrtf(sq), 1e-8f);
            float s0 = ss_l[0] * d0 / mn;
            float s1 = ss_l[1] * d1 / mn;
            a0 = __expf(fminf(s0, 60.f));
            a1 = __expf(fminf(s1, 60.f));
            e[row] = a0;
            e[NN + row] = a1;
        }
        a0 = wave_sum(a0); a1 = wave_sum(a1);
        __syncthreads();
        if (lane == 0) { red[w] = a0; red[4 + w] = a1; }
        __syncthreads();
        if (t == 0) {
            psum[blockIdx.x]        = red[0] + red[1] + red[2] + red[3];
            psum[8192 + blockIdx.x] = red[4] + red[5] + red[6] + red[7];
        }
    }
}

// K4: shift + sharpen (unchanged from R7)
__global__ __launch_bounds__(256) void shift_pow_kernel(
    const float* __restrict__ e, const float* __restrict__ pw,
    const float* __restrict__ params, const float* __restrict__ psum,
    float* __restrict__ wp, float* __restrict__ psum2)
{
    __shared__ float par[6];
    __shared__ float shs[6];
    __shared__ float red[8];
    int t = threadIdx.x;
    int w = t >> 6, lane = t & 63;
    {
        float v0 = 0.f, v1 = 0.f;
        for (int i = t; i < 8192; i += 256) { v0 += psum[i]; v1 += psum[8192 + i]; }
        v0 = wave_sum(v0); v1 = wave_sum(v1);
        if (lane == 0) { red[w] = v0; red[4 + w] = v1; }
        __syncthreads();
        if (t == 0) {
            par[0] = 1.0f / (red[0] + red[1] + red[2] + red[3]);
            par[1] = 1.0f / (red[4] + red[5] + red[6] + red[7]);
            par[2] = sigm(params[P_RAWG]);
            par[3] = sigm(params[P_RAWG + 1]);
            par[4] = 1.0f + softplus_(params[P_RAWGA]);
            par[5] = 1.0f + softplus_(params[P_RAWGA + 1]);
        }
        if (t == 64) {
            #pragma unroll
            for (int h = 0; h < 2; h++) {
                float s0 = params[P_RAWS + h * 3], s1 = params[P_RAWS + h * 3 + 1], s2 = params[P_RAWS + h * 3 + 2];
                float mx = fmaxf(s0, fmaxf(s1, s2));
                float e0 = expf(s0 - mx), e1 = expf(s1 - mx), e2 = expf(s2 - mx);
                float inv = 1.0f / (e0 + e1 + e2);
                shs[h * 3 + 0] = e0 * inv;
                shs[h * 3 + 1] = e1 * inv;
                shs[h * 3 + 2] = e2 * inv;
            }
        }
        __syncthreads();
    }
    float gate0 = par[2], gate1 = par[3];
    float inv0 = par[0], inv1 = par[1];
    float ga0 = par[4], ga1 = par[5];
    float sh00 = shs[0], sh01 = shs[1], sh02 = shs[2];
    float sh10 = shs[3], sh11 = shs[4], sh12 = shs[5];
    int tid = blockIdx.x * 256 + t;
    float a0 = 0.f, a1 = 0.f;
    #pragma unroll
    for (int h = 0; h < 2; h++) {
        int n = tid;
        int base = h << 17;
        float gate = h ? gate1 : gate0, inv = h ? inv1 : inv0, gamma = h ? ga1 : ga0;
        float s0 = h ? sh10 : sh00, s1 = h ? sh11 : sh01, s2 = h ? sh12 : sh02;
        int nm = (n - 1) & (NN - 1), np = (n + 1) & (NN - 1);
        float gwm = gate * e[base + nm] * inv + (1.f - gate) * pw[base + nm];
        float gw0 = gate * e[base + n] * inv + (1.f - gate) * pw[base + n];
        float gwp = gate * e[base + np] * inv + (1.f - gate) * pw[base + np];
        float sw = s0 * gwm + s1 * gw0 + s2 * gwp;
        float v = __powf(sw, gamma);
        wp[base + n] = v;
        if (h) a1 += v; else a0 += v;
    }
    a0 = wave_sum(a0); a1 = wave_sum(a1);
    __syncthreads();
    if (lane == 0) { red[w] = a0; red[4 + w] = a1; }
    __syncthreads();
    if (t == 0) {
        psum2[blockIdx.x]       = red[0] + red[1] + red[2] + red[3];
        psum2[512 + blockIdx.x] = red[4] + red[5] + red[6] + red[7];
    }
}

// K5: update — R7 structure (plain loads, NT stores), DIAGNOSTIC x2 repeat
__global__ __launch_bounds__(256) void update_kernel(
    const float* __restrict__ mem, const float* __restrict__ wp,
    const float* __restrict__ psum2, const float* __restrict__ er, const float* __restrict__ ad,
    float* __restrict__ newmem, float* __restrict__ rpart)
{
    __shared__ float sc_l[2];
    __shared__ float red[8];
    __shared__ float lds[4][256];
    int t = threadIdx.x;
    int w = t >> 6, lane = t & 63;
    {
        float v0 = 0.f, v1 = 0.f;
        for (int i = t; i < 512; i += 256) { v0 += psum2[i]; v1 += psum2[512 + i]; }
        v0 = wave_sum(v0); v1 = wave_sum(v1);
        if (lane == 0) { red[w] = v0; red[4 + w] = v1; }
        __syncthreads();
        if (t == 0) {
            sc_l[0] = 1.0f / (red[0] + red[1] + red[2] + red[3] + 1e-16f);
            sc_l[1] = 1.0f / (red[4] + red[5] + red[6] + red[7] + 1e-16f);
        }
        __syncthreads();
    }
    float sc0 = sc_l[0], sc1 = sc_l[1];
    int wid = blockIdx.x * 4 + w;  // 0..4095, 32 rows each
    float4 e4 = ((const float4*)er)[lane];
    float4 a4 = ((const float4*)ad)[lane];
    const float4* m4 = (const float4*)mem;
    nat_f4* o4 = (nat_f4*)newmem;
    for (int rep = 0; rep < 2; rep++) {    // DIAGNOSTIC repeat
        float4 acc = make_float4(0.f, 0.f, 0.f, 0.f);
        for (int r = 0; r < 32; r++) {
            int row = wid * 32 + r;
            float wr = wp[row] * sc0;
            float ww = wp[NN + row] * sc1;
            float4 mv = m4[(size_t)row * 64 + lane];
            nat_f4 nm;
            nm.x = mv.x * (1.f - ww * e4.x) + ww * a4.x;
            nm.y = mv.y * (1.f - ww * e4.y) + ww * a4.y;
            nm.z = mv.z * (1.f - ww * e4.z) + ww * a4.z;
            nm.w = mv.w * (1.f - ww * e4.w) + ww * a4.w;
            __builtin_nontemporal_store(nm, &o4[(size_t)row * 64 + lane]);
            acc.x += wr * mv.x; acc.y += wr * mv.y; acc.z += wr * mv.z; acc.w += wr * mv.w;
        }
        lds[w][lane * 4 + 0] = acc.x;
        lds[w][lane * 4 + 1] = acc.y;
        lds[w][lane * 4 + 2] = acc.z;
        lds[w][lane * 4 + 3] = acc.w;
        __syncthreads();
        float s = lds[0][t] + lds[1][t] + lds[2][t] + lds[3][t];
        rpart[(size_t)blockIdx.x * 256 + t] = s;
        __syncthreads();   // protect lds before next rep
    }
}

// K6: read partial column reduction
__global__ __launch_bounds__(256) void read_reduce_kernel(
    const float* __restrict__ rpart, float* __restrict__ readv)
{
    int m = blockIdx.x;  // 0..255
    int t = threadIdx.x;
    float s = 0.f;
    #pragma unroll
    for (int k = 0; k < 4; k++) s += rpart[(size_t)(t + 256 * k) * 256 + m];
    s = wave_sum(s);
    __shared__ float l[4];
    int w = t >> 6, lane = t & 63;
    if (lane == 0) l[w] = s;
    __syncthreads();
    if (t == 0) readv[m] = l[0] + l[1] + l[2] + l[3];
}

// K7: output projection
__global__ __launch_bounds__(256) void out_kernel(
    const float* __restrict__ gates, const float* __restrict__ cs,
    const float* __restrict__ readv,
    const float* __restrict__ Wout, const float* __restrict__ bout, float* __restrict__ out)
{
    __shared__ float hl[1280];
    int t = threadIdx.x;
    #pragma unroll
    for (int k = 0; k < 4; k++) {
        int j = t + 256 * k;
        float ig = gates[j], fg = gates[1024 + j], gg = gates[2048 + j], og = gates[3072 + j];
        float cv = sigm(fg) * cs[j] + sigm(ig) * tanhf(gg);
        hl[j] = sigm(og) * tanhf(cv);
    }
    hl[1024 + t] = readv[t];
    __syncthreads();

    int wid = blockIdx.x * 4 + (t >> 6);  // 0..511
    int lane = t & 63;
    const float4* w4 = (const float4*)(Wout + (size_t)wid * 1280);
    const float4* h4 = (const float4*)hl;
    float s = 0.f;
    #pragma unroll
    for (int q = 0; q < 5; q++) {
        int j4 = lane + 64 * q;
        s += dot4(w4[j4], h4[j4]);
    }
    s = wave_sum(s);
    if (lane == 0) out[wid] = sigm(s + bout[wid]);
}

extern "C" void kernel_launch(void* const* d_in, const int* in_sizes, int n_in,
                              void* d_out, int out_size, void* d_ws, size_t ws_size,
                              hipStream_t stream)
{
    const float* x       = (const float*)d_in[0];
    const float* pr      = (const float*)d_in[1];
    const float* hs      = (const float*)d_in[2];
    const float* cs      = (const float*)d_in[3];
    const float* mem     = (const float*)d_in[4];
    const float* pw      = (const float*)d_in[5];
    const float* Wih     = (const float*)d_in[6];
    const float* bih     = (const float*)d_in[7];
    const float* Whh     = (const float*)d_in[8];
    const float* bhh     = (const float*)d_in[9];
    const float* Wout    = (const float*)d_in[10];
    const float* bout    = (const float*)d_in[11];
    const float* Wk      = (const float*)d_in[12];
    const float* bk      = (const float*)d_in[13];
    const float* Wbeta   = (const float*)d_in[14];
    const float* bbeta   = (const float*)d_in[15];
    const float* Wg      = (const float*)d_in[16];
    const float* bg      = (const float*)d_in[17];
    const float* Ws      = (const float*)d_in[18];
    const float* bs      = (const float*)d_in[19];
    const float* Wgamma  = (const float*)d_in[20];
    const float* bgamma  = (const float*)d_in[21];
    const float* We      = (const float*)d_in[22];
    const float* be      = (const float*)d_in[23];
    const float* Wa      = (const float*)d_in[24];
    const float* ba      = (const float*)d_in[25];

    float* ws = (float*)d_ws;
    float* P      = ws + WS_P;
    float* gates  = ws + WS_GATES;
    float* key    = ws + WS_KEY;
    float* er     = ws + WS_ER;
    float* ad     = ws + WS_AD;
    float* e      = ws + WS_E;
    float* wp     = ws + WS_WP;
    float* psum   = ws + WS_PSUM;
    float* psum2  = ws + WS_PSUM2;
    float* rpart  = ws + WS_RPART;
    float* readv  = ws + WS_READ;

    float* out    = (float*)d_out;          // [512]
    float* newmem = (float*)d_out + 512;    // [N*M]

    gates_kernel<<<1024, 256, 0, stream>>>(x, pr, hs, Wih, bih, Whh, bhh, gates);
    head_prep_kernel<<<259, 256, 0, stream>>>(gates, cs, Wk, bk, We, be, Wa, ba, Ws, bs,
                                              Wbeta, bbeta, Wg, bg, Wgamma, bgamma,
                                              key, er, ad, P);
    score_exp_kernel<<<8192, 256, 0, stream>>>(mem, key, P, e, psum);
    shift_pow_kernel<<<512, 256, 0, stream>>>(e, pw, P, psum, wp, psum2);
    update_kernel<<<1024, 256, 0, stream>>>(mem, wp, psum2, er, ad, newmem, rpart);
    read_reduce_kernel<<<256, 256, 0, stream>>>(rpart, readv);
    out_kernel<<<128, 256, 0, stream>>>(gates, cs, readv, Wout, bout, out);
}

// Round 14
// 106.571 us; speedup vs baseline: 1.9122x; 1.9122x over previous
//
#include <hip/hip_runtime.h>
#include <math.h>

#define NN 131072
#define MM 256
#define HH 1024

typedef float nat_f4 __attribute__((ext_vector_type(4)));

// ---------------- ws layout (float offsets) ----------------
#define WS_P      0        // raw params[32]
#define WS_GATES  64       // 4096
#define WS_KEY    4160     // 2*256
#define WS_ER     4672     // 256
#define WS_AD     4928     // 256
#define WS_E      8192     // 2*N  (exp(score), unnormalized)
#define WS_WP     270336   // 2*N
#define WS_PSUM   532480   // 2*8192
#define WS_PSUM2  548864   // 2*512
#define WS_RPART  549888   // 1024*256
#define WS_READ   812032   // 256

// raw params indices (written by head_prep, consumed redundantly per block)
#define P_RAWB   0   // raw beta [2]
#define P_RAWG   2   // raw gate [2]
#define P_RAWGA  4   // raw gamma [2]
#define P_RAWS   6   // raw shift [2][3]

__device__ __forceinline__ float wave_sum(float v) {
    v += __shfl_xor(v, 32); v += __shfl_xor(v, 16); v += __shfl_xor(v, 8);
    v += __shfl_xor(v, 4);  v += __shfl_xor(v, 2);  v += __shfl_xor(v, 1);
    return v;
}
__device__ __forceinline__ float sigm(float x) { return 1.0f / (1.0f + expf(-x)); }
__device__ __forceinline__ float softplus_(float x) { return x > 20.0f ? x : log1pf(expf(x)); }
__device__ __forceinline__ float dot4(float4 a, float4 b) {
    return a.x * b.x + a.y * b.y + a.z * b.z + a.w * b.w;
}

// K1: gates[g] = W_ih[g,:]·lstm_in + b_ih[g] + W_hh[g,:]·h_state + b_hh[g]
__global__ __launch_bounds__(256) void gates_kernel(
    const float* __restrict__ x, const float* __restrict__ pr, const float* __restrict__ hs,
    const float* __restrict__ Wih, const float* __restrict__ bih,
    const float* __restrict__ Whh, const float* __restrict__ bhh,
    float* __restrict__ gates)
{
    int wid = blockIdx.x * 4 + (threadIdx.x >> 6);   // 0..4095
    int lane = threadIdx.x & 63;
    const float4* wi4 = (const float4*)(Wih + (size_t)wid * 768);
    const float4* wh4 = (const float4*)(Whh + (size_t)wid * 1024);
    const float4* x4  = (const float4*)x;
    const float4* pr4 = (const float4*)pr;
    const float4* hs4 = (const float4*)hs;
    float s = 0.f;
    #pragma unroll
    for (int q = 0; q < 3; q++) {
        int j4 = lane + 64 * q;                       // 0..191
        float4 wv = wi4[j4];
        float4 xv = (q < 2) ? x4[j4] : pr4[j4 - 128]; // q uniform: no divergence
        s += dot4(wv, xv);
    }
    #pragma unroll
    for (int q = 0; q < 4; q++) {
        int j4 = lane + 64 * q;                       // 0..255
        s += dot4(wh4[j4], hs4[j4]);
    }
    s = wave_sum(s);
    if (lane == 0) gates[wid] = s + bih[wid] + bhh[wid];
}

// K2: head linears. Each block recomputes c from gates into LDS, then one
// wave per output row (key/erase/add/shift/scalars).
__global__ __launch_bounds__(256) void head_prep_kernel(
    const float* __restrict__ gates, const float* __restrict__ cs,
    const float* __restrict__ Wk, const float* __restrict__ bk,
    const float* __restrict__ We, const float* __restrict__ be,
    const float* __restrict__ Wa, const float* __restrict__ ba,
    const float* __restrict__ Ws, const float* __restrict__ bs,
    const float* __restrict__ Wbeta, const float* __restrict__ bbeta,
    const float* __restrict__ Wg, const float* __restrict__ bg,
    const float* __restrict__ Wgamma, const float* __restrict__ bgamma,
    float* __restrict__ key, float* __restrict__ er, float* __restrict__ ad,
    float* __restrict__ params)
{
    __shared__ float c_l[1024];
    int t = threadIdx.x;
    #pragma unroll
    for (int k = 0; k < 4; k++) {
        int j = t + 256 * k;
        float ig = gates[j], fg = gates[1024 + j], gg = gates[2048 + j];
        c_l[j] = sigm(fg) * cs[j] + sigm(ig) * tanhf(gg);
    }
    __syncthreads();

    int wid = blockIdx.x * 4 + (t >> 6);   // 0..1035 (259*4 = 1036 exactly)
    int lane = t & 63;
    const float* wrow; float bias; float* dst; int act;
    if (wid < 512)      { int h = wid >> 8, m = wid & 255; wrow = Wk + (size_t)(h * 256 + m) * 1024; bias = bk[h * 256 + m]; dst = key + wid; act = 0; }
    else if (wid < 768) { int m = wid - 512; wrow = We + (size_t)(256 + m) * 1024; bias = be[256 + m]; dst = er + m; act = 1; }
    else if (wid < 1024){ int m = wid - 768; wrow = Wa + (size_t)(256 + m) * 1024; bias = ba[256 + m]; dst = ad + m; act = 0; }
    else if (wid < 1030){ int k = wid - 1024; wrow = Ws + (size_t)k * 1024; bias = bs[k]; dst = params + P_RAWS + k; act = 2; }
    else                { int k = wid - 1030; int h = k & 1, which = k >> 1;
                          const float* Wp = which == 0 ? Wbeta : (which == 1 ? Wg : Wgamma);
                          const float* bp = which == 0 ? bbeta : (which == 1 ? bg : bgamma);
                          wrow = Wp + h * 1024; bias = bp[h]; dst = params + 2 * which + h; act = 2; }
    const float4* w4 = (const float4*)wrow;
    const float4* c4 = (const float4*)c_l;
    float s = 0.f;
    #pragma unroll
    for (int q = 0; q < 4; q++) {
        int j4 = lane + 64 * q;
        s += dot4(w4[j4], c4[j4]);
    }
    s = wave_sum(s);
    if (lane == 0) {
        s += bias;
        if (act == 0) s = tanhf(s);
        else if (act == 1) s = sigm(s);
        *dst = s;
    }
}

// K3: big pass 1 — cosine scores for both heads, exp inline, block partial
// sums. Key norms + beta scale computed per-block from key.
__global__ __launch_bounds__(256) void score_exp_kernel(
    const float* __restrict__ mem, const float* __restrict__ key,
    const float* __restrict__ params, float* __restrict__ e, float* __restrict__ psum)
{
    __shared__ float ss_l[2];
    __shared__ float red[8];
    int t = threadIdx.x;
    int w = t >> 6, lane = t & 63;
    {   // block-redundant: kn + sscale for both heads (identical FP order
        // across blocks -> deterministic, bit-identical everywhere)
        float v0 = key[t], v1 = key[256 + t];
        float s0 = v0 * v0, s1 = v1 * v1;
        s0 = wave_sum(s0); s1 = wave_sum(s1);
        if (lane == 0) { red[w] = s0; red[4 + w] = s1; }
        __syncthreads();
        if (t == 0) {
            float k0 = red[0] + red[1] + red[2] + red[3];
            float k1 = red[4] + red[5] + red[6] + red[7];
            ss_l[0] = softplus_(params[P_RAWB])     / fmaxf(sqrtf(k0), 1e-8f);
            ss_l[1] = softplus_(params[P_RAWB + 1]) / fmaxf(sqrtf(k1), 1e-8f);
        }
        __syncthreads();
    }
    int sub = lane & 15, g = lane >> 4;
    int wid = blockIdx.x * 4 + w;          // 0..32767
    int row = wid * 4 + g;                 // 0..131071
    const float4* m4 = (const float4*)mem;
    const float4* k4 = (const float4*)key;
    float4 k0[4], k1[4], mv[4];
    #pragma unroll
    for (int q = 0; q < 4; q++) {
        k0[q] = k4[sub + 16 * q];
        k1[q] = k4[64 + sub + 16 * q];
        mv[q] = m4[(size_t)row * 64 + sub + 16 * q];
    }
    float d0 = 0.f, d1 = 0.f, sq = 0.f;
    #pragma unroll
    for (int q = 0; q < 4; q++) {
        d0 += dot4(k0[q], mv[q]);
        d1 += dot4(k1[q], mv[q]);
        sq += dot4(mv[q], mv[q]);
    }
    #pragma unroll
    for (int off = 8; off; off >>= 1) {
        d0 += __shfl_xor(d0, off); d1 += __shfl_xor(d1, off); sq += __shfl_xor(sq, off);
    }
    float a0 = 0.f, a1 = 0.f;
    if (sub == 0) {
        float mn = fmaxf(sqrtf(sq), 1e-8f);
        float s0 = ss_l[0] * d0 / mn;
        float s1 = ss_l[1] * d1 / mn;
        a0 = __expf(fminf(s0, 60.f));
        a1 = __expf(fminf(s1, 60.f));
        e[row] = a0;
        e[NN + row] = a1;
    }
    a0 = wave_sum(a0); a1 = wave_sum(a1);
    __syncthreads();   // red[] reuse
    if (lane == 0) { red[w] = a0; red[4 + w] = a1; }
    __syncthreads();
    if (t == 0) {
        psum[blockIdx.x]        = red[0] + red[1] + red[2] + red[3];
        psum[8192 + blockIdx.x] = red[4] + red[5] + red[6] + red[7];
    }
}

// K4: gated interpolation + circular 3-tap shift + sharpening, partial sums.
// Softmax denom + gate/gamma/shift computed per-block.
__global__ __launch_bounds__(256) void shift_pow_kernel(
    const float* __restrict__ e, const float* __restrict__ pw,
    const float* __restrict__ params, const float* __restrict__ psum,
    float* __restrict__ wp, float* __restrict__ psum2)
{
    __shared__ float par[6];
    __shared__ float shs[6];
    __shared__ float red[8];
    int t = threadIdx.x;
    int w = t >> 6, lane = t & 63;
    {   // block-redundant softmax-denominator reduction (fixed order)
        float v0 = 0.f, v1 = 0.f;
        for (int i = t; i < 8192; i += 256) { v0 += psum[i]; v1 += psum[8192 + i]; }
        v0 = wave_sum(v0); v1 = wave_sum(v1);
        if (lane == 0) { red[w] = v0; red[4 + w] = v1; }
        __syncthreads();
        if (t == 0) {
            par[0] = 1.0f / (red[0] + red[1] + red[2] + red[3]);   // inv0
            par[1] = 1.0f / (red[4] + red[5] + red[6] + red[7]);   // inv1
            par[2] = sigm(params[P_RAWG]);                          // gate0
            par[3] = sigm(params[P_RAWG + 1]);                      // gate1
            par[4] = 1.0f + softplus_(params[P_RAWGA]);             // gamma0
            par[5] = 1.0f + softplus_(params[P_RAWGA + 1]);         // gamma1
        }
        if (t == 64) {   // shift softmaxes (other wave, runs concurrently)
            #pragma unroll
            for (int h = 0; h < 2; h++) {
                float s0 = params[P_RAWS + h * 3], s1 = params[P_RAWS + h * 3 + 1], s2 = params[P_RAWS + h * 3 + 2];
                float mx = fmaxf(s0, fmaxf(s1, s2));
                float e0 = expf(s0 - mx), e1 = expf(s1 - mx), e2 = expf(s2 - mx);
                float inv = 1.0f / (e0 + e1 + e2);
                shs[h * 3 + 0] = e0 * inv;
                shs[h * 3 + 1] = e1 * inv;
                shs[h * 3 + 2] = e2 * inv;
            }
        }
        __syncthreads();
    }
    float gate0 = par[2], gate1 = par[3];
    float inv0 = par[0], inv1 = par[1];
    float ga0 = par[4], ga1 = par[5];
    float sh00 = shs[0], sh01 = shs[1], sh02 = shs[2];
    float sh10 = shs[3], sh11 = shs[4], sh12 = shs[5];
    int tid = blockIdx.x * 256 + t;  // 512 blocks
    float a0 = 0.f, a1 = 0.f;
    #pragma unroll
    for (int h = 0; h < 2; h++) {
        int n = tid;
        int base = h << 17;
        float gate = h ? gate1 : gate0, inv = h ? inv1 : inv0, gamma = h ? ga1 : ga0;
        float s0 = h ? sh10 : sh00, s1 = h ? sh11 : sh01, s2 = h ? sh12 : sh02;
        int nm = (n - 1) & (NN - 1), np = (n + 1) & (NN - 1);
        float gwm = gate * e[base + nm] * inv + (1.f - gate) * pw[base + nm];
        float gw0 = gate * e[base + n] * inv + (1.f - gate) * pw[base + n];
        float gwp = gate * e[base + np] * inv + (1.f - gate) * pw[base + np];
        float sw = s0 * gwm + s1 * gw0 + s2 * gwp;
        float v = __powf(sw, gamma);
        wp[base + n] = v;
        if (h) a1 += v; else a0 += v;
    }
    a0 = wave_sum(a0); a1 = wave_sum(a1);
    __syncthreads();   // red[] reuse
    if (lane == 0) { red[w] = a0; red[4 + w] = a1; }
    __syncthreads();
    if (t == 0) {
        psum2[blockIdx.x]       = red[0] + red[1] + red[2] + red[3];
        psum2[512 + blockIdx.x] = red[4] + red[5] + red[6] + red[7];
    }
}

// K5: big pass 2 — fused memory update + read-vector partials. Plain loads
// (L3-served after score), NT stores (don't evict mem from L3). Measured
// (R11): 268 MB true traffic in 40us = 6.7 TB/s effective -> at roofline.
__global__ __launch_bounds__(256) void update_kernel(
    const float* __restrict__ mem, const float* __restrict__ wp,
    const float* __restrict__ psum2, const float* __restrict__ er, const float* __restrict__ ad,
    float* __restrict__ newmem, float* __restrict__ rpart)
{
    __shared__ float sc_l[2];
    __shared__ float red[8];
    int t = threadIdx.x;
    int w = t >> 6, lane = t & 63;
    {   // block-redundant sharpening-denominator reduction (fixed order)
        float v0 = 0.f, v1 = 0.f;
        for (int i = t; i < 512; i += 256) { v0 += psum2[i]; v1 += psum2[512 + i]; }
        v0 = wave_sum(v0); v1 = wave_sum(v1);
        if (lane == 0) { red[w] = v0; red[4 + w] = v1; }
        __syncthreads();
        if (t == 0) {
            sc_l[0] = 1.0f / (red[0] + red[1] + red[2] + red[3] + 1e-16f);
            sc_l[1] = 1.0f / (red[4] + red[5] + red[6] + red[7] + 1e-16f);
        }
        __syncthreads();
    }
    float sc0 = sc_l[0], sc1 = sc_l[1];
    int wid = blockIdx.x * 4 + w;  // 0..4095, 32 rows each
    float4 e4 = ((const float4*)er)[lane];
    float4 a4 = ((const float4*)ad)[lane];
    float4 acc = make_float4(0.f, 0.f, 0.f, 0.f);
    const float4* m4 = (const float4*)mem;
    nat_f4* o4 = (nat_f4*)newmem;
    for (int r = 0; r < 32; r++) {
        int row = wid * 32 + r;
        float wr = wp[row] * sc0;
        float ww = wp[NN + row] * sc1;
        float4 mv = m4[(size_t)row * 64 + lane];
        nat_f4 nm;
        nm.x = mv.x * (1.f - ww * e4.x) + ww * a4.x;
        nm.y = mv.y * (1.f - ww * e4.y) + ww * a4.y;
        nm.z = mv.z * (1.f - ww * e4.z) + ww * a4.z;
        nm.w = mv.w * (1.f - ww * e4.w) + ww * a4.w;
        __builtin_nontemporal_store(nm, &o4[(size_t)row * 64 + lane]);
        acc.x += wr * mv.x; acc.y += wr * mv.y; acc.z += wr * mv.z; acc.w += wr * mv.w;
    }
    __shared__ float lds[4][256];
    lds[w][lane * 4 + 0] = acc.x;
    lds[w][lane * 4 + 1] = acc.y;
    lds[w][lane * 4 + 2] = acc.z;
    lds[w][lane * 4 + 3] = acc.w;
    __syncthreads();
    float s = lds[0][t] + lds[1][t] + lds[2][t] + lds[3][t];
    rpart[(size_t)blockIdx.x * 256 + t] = s;
}

// K6: reduce read partials — one block per output element m, column sum.
__global__ __launch_bounds__(256) void read_reduce_kernel(
    const float* __restrict__ rpart, float* __restrict__ readv)
{
    int m = blockIdx.x;  // 0..255
    int t = threadIdx.x;
    float s = 0.f;
    #pragma unroll
    for (int k = 0; k < 4; k++) s += rpart[(size_t)(t + 256 * k) * 256 + m];
    s = wave_sum(s);
    __shared__ float l[4];
    int w = t >> 6, lane = t & 63;
    if (lane == 0) l[w] = s;
    __syncthreads();
    if (t == 0) readv[m] = l[0] + l[1] + l[2] + l[3];
}

// K7: out = sigmoid([h, read] @ W_out.T + b_out); h recomputed from gates.
__global__ __launch_bounds__(256) void out_kernel(
    const float* __restrict__ gates, const float* __restrict__ cs,
    const float* __restrict__ readv,
    const float* __restrict__ Wout, const float* __restrict__ bout, float* __restrict__ out)
{
    __shared__ float hl[1280];
    int t = threadIdx.x;
    #pragma unroll
    for (int k = 0; k < 4; k++) {
        int j = t + 256 * k;
        float ig = gates[j], fg = gates[1024 + j], gg = gates[2048 + j], og = gates[3072 + j];
        float cv = sigm(fg) * cs[j] + sigm(ig) * tanhf(gg);
        hl[j] = sigm(og) * tanhf(cv);
    }
    hl[1024 + t] = readv[t];
    __syncthreads();

    int wid = blockIdx.x * 4 + (t >> 6);  // 0..511
    int lane = t & 63;
    const float4* w4 = (const float4*)(Wout + (size_t)wid * 1280);
    const float4* h4 = (const float4*)hl;
    float s = 0.f;
    #pragma unroll
    for (int q = 0; q < 5; q++) {
        int j4 = lane + 64 * q;
        s += dot4(w4[j4], h4[j4]);
    }
    s = wave_sum(s);
    if (lane == 0) out[wid] = sigm(s + bout[wid]);
}

extern "C" void kernel_launch(void* const* d_in, const int* in_sizes, int n_in,
                              void* d_out, int out_size, void* d_ws, size_t ws_size,
                              hipStream_t stream)
{
    const float* x       = (const float*)d_in[0];
    const float* pr      = (const float*)d_in[1];
    const float* hs      = (const float*)d_in[2];
    const float* cs      = (const float*)d_in[3];
    const float* mem     = (const float*)d_in[4];
    const float* pw      = (const float*)d_in[5];
    const float* Wih     = (const float*)d_in[6];
    const float* bih     = (const float*)d_in[7];
    const float* Whh     = (const float*)d_in[8];
    const float* bhh     = (const float*)d_in[9];
    const float* Wout    = (const float*)d_in[10];
    const float* bout    = (const float*)d_in[11];
    const float* Wk      = (const float*)d_in[12];
    const float* bk      = (const float*)d_in[13];
    const float* Wbeta   = (const float*)d_in[14];
    const float* bbeta   = (const float*)d_in[15];
    const float* Wg      = (const float*)d_in[16];
    const float* bg      = (const float*)d_in[17];
    const float* Ws      = (const float*)d_in[18];
    const float* bs      = (const float*)d_in[19];
    const float* Wgamma  = (const float*)d_in[20];
    const float* bgamma  = (const float*)d_in[21];
    const float* We      = (const float*)d_in[22];
    const float* be      = (const float*)d_in[23];
    const float* Wa      = (const float*)d_in[24];
    const float* ba      = (const float*)d_in[25];

    float* ws = (float*)d_ws;
    float* P      = ws + WS_P;
    float* gates  = ws + WS_GATES;
    float* key    = ws + WS_KEY;
    float* er     = ws + WS_ER;
    float* ad     = ws + WS_AD;
    float* e      = ws + WS_E;
    float* wp     = ws + WS_WP;
    float* psum   = ws + WS_PSUM;
    float* psum2  = ws + WS_PSUM2;
    float* rpart  = ws + WS_RPART;
    float* readv  = ws + WS_READ;

    float* out    = (float*)d_out;          // [512]
    float* newmem = (float*)d_out + 512;    // [N*M]

    gates_kernel<<<1024, 256, 0, stream>>>(x, pr, hs, Wih, bih, Whh, bhh, gates);
    head_prep_kernel<<<259, 256, 0, stream>>>(gates, cs, Wk, bk, We, be, Wa, ba, Ws, bs,
                                              Wbeta, bbeta, Wg, bg, Wgamma, bgamma,
                                              key, er, ad, P);
    score_exp_kernel<<<8192, 256, 0, stream>>>(mem, key, P, e, psum);
    shift_pow_kernel<<<512, 256, 0, stream>>>(e, pw, P, psum, wp, psum2);
    update_kernel<<<1024, 256, 0, stream>>>(mem, wp, psum2, er, ad, newmem, rpart);
    read_reduce_kernel<<<256, 256, 0, stream>>>(rpart, readv);
    out_kernel<<<128, 256, 0, stream>>>(gates, cs, readv, Wout, bout, out);
}